// Round 5
// baseline (2659.204 us; speedup 1.0000x reference)
//
#include <hip/hip_runtime.h>
#include <math.h>

// Problem constants (from reference)
#define B_   8
#define T_   128
#define E_   256
#define H_   512
#define G_   2048          // 4*H
#define NWG  128           // 1 WG per CU, co-resident
#define NTHR 512           // 8 waves = 8 batches
#define NCOL 4             // h-columns owned per WG (128*4 = 512)
#define NGC  16            // gate columns per WG
#define XPITCH 1025        // LDS pitch, column-major X (conflict-free)

typedef unsigned long long u64;

// ---------------------------------------------------------------------------
// ALGEBRA (unchanged): softmax sums to 1 over t and h_shared is t-invariant =>
// Rt == h_last; attention path is dead. Compute:
//   h_last = sharedLSTM(emb); M = h_last @ Wmh_t; out = taskLSTM(emb; X2+h@Whh_t+M)
//
// R5: per-WAVE independent recurrence (wave = batch), zero per-step LDS data
// reads and zero per-step __syncthreads (R4 post-mortem: dot's broadcast
// ds_read_b128 with 4-way conflicts ~2.0us/step; syncthreads coupled all
// waves to the slowest of 128 flags).
//  - lane l holds W[l*8..l*8+8)[c=0..16) in 128 VGPRs; h[b][l*8..+8) arrives
//    in registers straight from the coalesced global payload load.
//  - 16 column sums reduced by value-halving butterfly (17 shuffle-adds).
//  - gates per quad via 3 quad shuffles; cell state in a register.
//  - exchange: img[2][b][512] (b-major, coalesced) + flags[b][wg] monotonic
//    gen counters; producer: relaxed data stores -> s_waitcnt vmcnt(0) ->
//    relaxed flag store (no cache-maintenance fences).
//  - no-overwrite: publishing gen g+1 is data-dependent on having read gen g
//    (or g-dependent state), so flag>=g+1 from all => all reads of g done =>
//    writer of g+2 (same buffer as g) is safe.
// ---------------------------------------------------------------------------

__device__ __forceinline__ float sigf(float x) { return 1.0f / (1.0f + expf(-x)); }

// ws layout: img[2][4096] floats (32 KB), then flags[8*128] unsigned (4 KB)
#define FLAGS_OFF 8192

__global__ void init_ws(float* ws) {
  unsigned* flags = (unsigned*)(ws + FLAGS_OFF);
  int i = blockIdx.x * blockDim.x + threadIdx.x;
  if (i < B_ * NWG) flags[i] = 0u;   // ws is poisoned 0xAA -> must zero flags
}

// Stage 512x16 column-slice of a (512 x 2048) recurrent weight, K-MAJOR:
// Wl2[k*16 + c] = W[k][(c>>2)*H + wg*4 + (c&3)]
__device__ __forceinline__ void load_wk(const float* __restrict__ W, int wg,
                                        float* __restrict__ Wl2) {
  for (int idx = threadIdx.x; idx < H_ * NGC; idx += NTHR) {
    int k = idx >> 4, c = idx & 15;
    Wl2[idx] = W[k * G_ + ((c >> 2) * H_ + wg * NCOL + (c & 3))];
  }
}

// Per-lane register weight slice: wrk[kk*4+cg] = W rows l*8+kk, cols cg*4..cg*4+3
__device__ __forceinline__ void load_wrk(const float* __restrict__ Wl2, int l,
                                         float4* __restrict__ wrk) {
#pragma unroll
  for (int kk = 0; kk < 8; ++kk) {
    const float4* pw = (const float4*)(Wl2 + (l * 8 + kk) * 16);
    wrk[kk * 4 + 0] = pw[0];
    wrk[kk * 4 + 1] = pw[1];
    wrk[kk * 4 + 2] = pw[2];
    wrk[kk * 4 + 3] = pw[3];
  }
}

// Poll gen's flags, load h[b] payload (coalesced, registers), dot with wrk,
// butterfly-reduce. Returns the full column sum for c = bitrev4(l&15).
__device__ __forceinline__ float rec_dot(const float* __restrict__ img,
                                         const unsigned* __restrict__ flags,
                                         unsigned gen, int b, int l,
                                         const float4* __restrict__ wrk) {
  const unsigned* fl = flags + b * NWG;
  while (__hip_atomic_load(&fl[l], __ATOMIC_RELAXED, __HIP_MEMORY_SCOPE_AGENT) < gen ||
         __hip_atomic_load(&fl[64 + l], __ATOMIC_RELAXED, __HIP_MEMORY_SCOPE_AGENT) < gen)
    __builtin_amdgcn_s_sleep(1);

  const u64* src = (const u64*)(img + (gen & 1u) * 4096 + b * H_) + (size_t)l * 4;
  u64 v[4];
#pragma unroll
  for (int j = 0; j < 4; ++j)
    v[j] = __hip_atomic_load(src + j, __ATOMIC_RELAXED, __HIP_MEMORY_SCOPE_AGENT);
  float h8[8];
#pragma unroll
  for (int j = 0; j < 4; ++j) {
    h8[2 * j]     = __uint_as_float((unsigned)v[j]);
    h8[2 * j + 1] = __uint_as_float((unsigned)(v[j] >> 32));
  }

  float acc[16];
#pragma unroll
  for (int c = 0; c < 16; ++c) acc[c] = 0.0f;
#pragma unroll
  for (int kk = 0; kk < 8; ++kk) {
    float hv = h8[kk];
    float4 w0 = wrk[kk * 4 + 0], w1 = wrk[kk * 4 + 1];
    float4 w2 = wrk[kk * 4 + 2], w3 = wrk[kk * 4 + 3];
    acc[0]  += hv * w0.x; acc[1]  += hv * w0.y; acc[2]  += hv * w0.z; acc[3]  += hv * w0.w;
    acc[4]  += hv * w1.x; acc[5]  += hv * w1.y; acc[6]  += hv * w1.z; acc[7]  += hv * w1.w;
    acc[8]  += hv * w2.x; acc[9]  += hv * w2.y; acc[10] += hv * w2.z; acc[11] += hv * w2.w;
    acc[12] += hv * w3.x; acc[13] += hv * w3.y; acc[14] += hv * w3.z; acc[15] += hv * w3.w;
  }

  // value-halving butterfly; final c per lane = bitrev4(l&15)
  float o8[8];
#pragma unroll
  for (int j = 0; j < 8; ++j) {
    float send = (l & 1) ? acc[j] : acc[8 + j];
    float keep = (l & 1) ? acc[8 + j] : acc[j];
    o8[j] = keep + __shfl_xor(send, 1);
  }
  float o4[4];
#pragma unroll
  for (int j = 0; j < 4; ++j) {
    float send = (l & 2) ? o8[j] : o8[4 + j];
    float keep = (l & 2) ? o8[4 + j] : o8[j];
    o4[j] = keep + __shfl_xor(send, 2);
  }
  float o2[2];
#pragma unroll
  for (int j = 0; j < 2; ++j) {
    float send = (l & 4) ? o4[j] : o4[2 + j];
    float keep = (l & 4) ? o4[2 + j] : o4[j];
    o2[j] = keep + __shfl_xor(send, 4);
  }
  float send = (l & 8) ? o2[0] : o2[1];
  float keep = (l & 8) ? o2[1] : o2[0];
  float vv = keep + __shfl_xor(send, 8);
  vv += __shfl_xor(vv, 16);
  vv += __shfl_xor(vv, 32);
  return vv;
}

// X[c][r] = sum_e emb[r][e]*Wih[e][col(c)] + bias[col(c)], r = t*8+b, col-major.
__device__ __forceinline__ void compute_X(const float* __restrict__ Wih,
                                          const float* __restrict__ bias,
                                          const int* __restrict__ tokens,
                                          const float* __restrict__ embed,
                                          int wg, float* __restrict__ Wbuf,
                                          float* __restrict__ Xlds,
                                          float* __restrict__ bias_lds) {
  const int tid = threadIdx.x;
  for (int idx = tid; idx < E_ * NGC; idx += NTHR) {     // 4096
    int e = idx >> 4, c = idx & 15;
    Wbuf[idx] = Wih[e * G_ + ((c >> 2) * H_ + wg * NCOL + (c & 3))];
  }
  if (tid < NGC) bias_lds[tid] = bias[(tid >> 2) * H_ + wg * NCOL + (tid & 3)];
  __syncthreads();

  const float4* er[2];
#pragma unroll
  for (int rr = 0; rr < 2; ++rr) {
    int r = tid + rr * NTHR;
    int tok = tokens[(r & 7) * T_ + (r >> 3)];           // tokens (B,T); r = t*8+b
    er[rr] = (const float4*)(embed + (size_t)tok * E_);
  }
  float acc[2][NGC];
#pragma unroll
  for (int rr = 0; rr < 2; ++rr)
#pragma unroll
    for (int cc = 0; cc < NGC; ++cc) acc[rr][cc] = bias_lds[cc];

  for (int ec = 0; ec < E_ / 4; ++ec) {
    float4 ev[2];
#pragma unroll
    for (int rr = 0; rr < 2; ++rr) ev[rr] = er[rr][ec];
    const float4* w4 = (const float4*)(Wbuf + ec * 64);  // 4 e's x 16 c
#pragma unroll
    for (int eo = 0; eo < 4; ++eo) {
      float wrow[16];
      *(float4*)(wrow + 0)  = w4[eo * 4 + 0];            // broadcast LDS reads
      *(float4*)(wrow + 4)  = w4[eo * 4 + 1];
      *(float4*)(wrow + 8)  = w4[eo * 4 + 2];
      *(float4*)(wrow + 12) = w4[eo * 4 + 3];
#pragma unroll
      for (int cc = 0; cc < NGC; ++cc) {
#pragma unroll
        for (int rr = 0; rr < 2; ++rr)
          acc[rr][cc] += reinterpret_cast<const float*>(&ev[rr])[eo] * wrow[cc];
      }
    }
  }
#pragma unroll
  for (int rr = 0; rr < 2; ++rr) {
    int r = tid + rr * NTHR;
#pragma unroll
    for (int cc = 0; cc < NGC; ++cc)
      Xlds[cc * XPITCH + r] = acc[rr][cc];               // conflict-free writes
  }
}

__global__ __launch_bounds__(NTHR, 1) void lstm_all(
    const int* __restrict__ tokens, const float* __restrict__ embed,
    const float* __restrict__ Wih_s, const float* __restrict__ Whh_s,
    const float* __restrict__ b_s,
    const float* __restrict__ Wih_t, const float* __restrict__ Whh_t,
    const float* __restrict__ Wmh_t, const float* __restrict__ b_t,
    float* __restrict__ out, float* __restrict__ ws) {
  __shared__ float Wl2[H_ * NGC];        // 32 KB k-major weight slice / Wih staging
  __shared__ float Xlds[NGC * XPITCH];   // 65.6 KB col-major X
  __shared__ float bias_lds[NGC];

  const int tid = threadIdx.x;
  const int wg  = blockIdx.x;
  const int l   = tid & 63;              // lane
  const int b   = tid >> 6;              // wave = batch
  float*    img   = ws;                  // img[2][4096]
  unsigned* flags = (unsigned*)(ws + FLAGS_OFF);

  // lane's owned gate column c = bitrev4(l&15); quad -> output col jj
  const int cown = ((l & 1) << 3) | ((l & 2) << 1) | ((l & 4) >> 1) | ((l & 8) >> 3);
  const int p    = l & 3;
  const int qd   = (l >> 2) & 3;
  const int jj   = ((qd & 1) << 1) | (qd >> 1);   // bitrev2(qd)
  const bool st_lane = (l < 16) && (p == 0);      // lanes 0,4,8,12 store cols {0,2,1,3}

  float4 wrk[32];   // 128 VGPRs: W[l*8..+8)[0..16)

  // ---------------- Phase A1: X1 = emb @ Wih_s + b_s
  compute_X(Wih_s, b_s, tokens, embed, wg, Wl2, Xlds, bias_lds);
  __syncthreads();
  load_wk(Whh_s, wg, Wl2);
  __syncthreads();
  load_wrk(Wl2, l, wrk);

  // ---------------- Phase B: shared LSTM (only h_last live); gens 1..128
  float c_reg = 0.0f;
  for (int t = 0; t < T_; ++t) {
    float d = (t > 0) ? rec_dot(img, flags, (unsigned)t, b, l, wrk) : 0.0f;
    float pre = d + Xlds[cown * XPITCH + t * 8 + b];
    float v1 = __shfl_xor(pre, 1), v2 = __shfl_xor(pre, 2), v3 = __shfl_xor(pre, 3);
    // value at quad position s: p^s selects {pre,v1,v2,v3}; pos0=i,1=g,2=f,3=o
    auto pick = [&](int x) { return x == 0 ? pre : (x == 1 ? v1 : (x == 2 ? v2 : v3)); };
    float gi = pick(p ^ 0), gg = pick(p ^ 1), gf = pick(p ^ 2), go = pick(p ^ 3);
    float cn = sigf(gf) * c_reg + sigf(gi) * tanhf(gg);
    float hn = sigf(go) * tanhf(cn);
    c_reg = cn;
    const unsigned gw = (unsigned)t + 1u;
    if (st_lane)
      __hip_atomic_store(img + (gw & 1u) * 4096 + b * H_ + wg * NCOL + jj, hn,
                         __ATOMIC_RELAXED, __HIP_MEMORY_SCOPE_AGENT);
    __builtin_amdgcn_s_waitcnt(0x0f70);   // vmcnt(0): data at coherence point
    if (l == 0)
      __hip_atomic_store(&flags[b * NWG + wg], gw,
                         __ATOMIC_RELAXED, __HIP_MEMORY_SCOPE_AGENT);
  }

  // ---------------- M = h_last @ Wmh_t (consume gen 128)
  __syncthreads();                  // all waves past phase B (Wl2 reload safe)
  load_wk(Wmh_t, wg, Wl2);
  __syncthreads();
  load_wrk(Wl2, l, wrk);
  float Mreg = rec_dot(img, flags, 128u, b, l, wrk);

  // ---------------- Phase A2: X2 = emb @ Wih_t + b_t
  __syncthreads();                  // all waves done reading Wl2/Xlds
  compute_X(Wih_t, b_t, tokens, embed, wg, Wl2, Xlds, bias_lds);
  __syncthreads();
  load_wk(Whh_t, wg, Wl2);
  __syncthreads();
  load_wrk(Wl2, l, wrk);

  // ---------------- Phase C: task LSTM; gens 129..255; out every step
  c_reg = 0.0f;
  for (int t = 0; t < T_; ++t) {
    float d = (t > 0) ? rec_dot(img, flags, 128u + (unsigned)t, b, l, wrk) : 0.0f;
    float pre = d + Xlds[cown * XPITCH + t * 8 + b] + Mreg;
    float v1 = __shfl_xor(pre, 1), v2 = __shfl_xor(pre, 2), v3 = __shfl_xor(pre, 3);
    auto pick = [&](int x) { return x == 0 ? pre : (x == 1 ? v1 : (x == 2 ? v2 : v3)); };
    float gi = pick(p ^ 0), gg = pick(p ^ 1), gf = pick(p ^ 2), go = pick(p ^ 3);
    float cn = sigf(gf) * c_reg + sigf(gi) * tanhf(gg);
    float hn = sigf(go) * tanhf(cn);
    c_reg = cn;
    if (st_lane) {
      out[b * (T_ * H_) + t * H_ + wg * NCOL + jj] = hn;
      if (t < T_ - 1) {
        const unsigned gw = 129u + (unsigned)t;
        __hip_atomic_store(img + (gw & 1u) * 4096 + b * H_ + wg * NCOL + jj, hn,
                           __ATOMIC_RELAXED, __HIP_MEMORY_SCOPE_AGENT);
      }
    }
    if (t < T_ - 1) {
      __builtin_amdgcn_s_waitcnt(0x0f70);
      if (l == 0)
        __hip_atomic_store(&flags[b * NWG + wg], 129u + (unsigned)t,
                           __ATOMIC_RELAXED, __HIP_MEMORY_SCOPE_AGENT);
    }
  }
}

extern "C" void kernel_launch(void* const* d_in, const int* in_sizes, int n_in,
                              void* d_out, int out_size, void* d_ws, size_t ws_size,
                              hipStream_t stream) {
  const int*   tokens = (const int*)d_in[0];
  // d_in[1] = TASK (unused)
  const float* embed  = (const float*)d_in[2];
  const float* Wih_s  = (const float*)d_in[3];
  const float* Whh_s  = (const float*)d_in[4];
  const float* b_s    = (const float*)d_in[5];
  // d_in[6..9] = Ws_w, Ws_b, Us_w, Us_b -> dead (attention collapses)
  const float* Wih_t  = (const float*)d_in[10];
  const float* Whh_t  = (const float*)d_in[11];
  const float* Wmh_t  = (const float*)d_in[12];
  const float* b_t    = (const float*)d_in[13];
  float* out = (float*)d_out;
  float* ws  = (float*)d_ws;

  hipLaunchKernelGGL(init_ws, dim3(1), dim3(1024), 0, stream, ws);
  hipLaunchKernelGGL(lstm_all, dim3(NWG), dim3(NTHR), 0, stream,
                     tokens, embed, Wih_s, Whh_s, b_s,
                     Wih_t, Whh_t, Wmh_t, b_t, out, ws);
}